// Round 1
// baseline (5560.418 us; speedup 1.0000x reference)
//
#include <hip/hip_runtime.h>
#include <hip/hip_bf16.h>
#include <math.h>

#define BGR   8192        // graphs
#define NND   9           // nodes per graph
#define BN    73728       // BGR*NND
#define NE    131072      // BGR*16 explicit edges
#define ETOT  204800      // NE + BN (self loops)
#define H     128
#define MH    256
#define FIN   15

// ---------------------------------------------------------------- deg kernel
__global__ void deg_kernel(const int* __restrict__ edges, float* __restrict__ inv_deg) {
    int g = blockIdx.x * 256 + threadIdx.x;
    if (g >= BGR) return;
    int cnt[NND];
#pragma unroll
    for (int n = 0; n < NND; ++n) cnt[n] = 1;   // self loop
    for (int j = 0; j < 16; ++j) {
        int d = edges[g * 32 + 16 + j];
#pragma unroll
        for (int n = 0; n < NND; ++n) cnt[n] += (d == n) ? 1 : 0;
    }
#pragma unroll
    for (int n = 0; n < NND; ++n) inv_deg[g * NND + n] = 1.0f / (float)cnt[n];
}

// ---------------------------------------------------------------- encoder
__global__ void enc_kernel(const float* __restrict__ obs, const float* __restrict__ W,
                           const float* __restrict__ b, float* __restrict__ x) {
    int tid = blockIdx.x * 256 + threadIdx.x;     // BN*128 threads
    int i = tid >> 7, h = tid & 127;
    float acc = b[h];
#pragma unroll
    for (int k = 0; k < FIN; ++k) acc += obs[i * FIN + k] * W[k * H + h];
    x[i * H + h] = tanhf(acc);
}

// ---------------------------------------------------------------- message MLP (32 edges / block)
// LDS layout: act[k][e] with row stride 36 (pad: write-conflict mitigation, float4-aligned)
__global__ __launch_bounds__(256, 2) void msg_kernel(
        const float* __restrict__ x, const int* __restrict__ edges,
        const float* __restrict__ W1, const float* __restrict__ b1,
        const float* __restrict__ W2, const float* __restrict__ b2,
        const float* __restrict__ W3, const float* __restrict__ b3,
        float* __restrict__ aggr) {
    __shared__ float mA[256 * 36];
    __shared__ float mB[256 * 36];
    __shared__ int ss[32], sd[32];
    const int t = threadIdx.x;
    const int e0 = blockIdx.x * 32;

    if (t < 32) {
        int e = e0 + t;
        int s_, d_;
        if (e < NE) {
            int g = e >> 4, j = e & 15;
            s_ = g * NND + edges[g * 32 + j];        // src row
            d_ = g * NND + edges[g * 32 + 16 + j];   // dst row
        } else {
            int i = e - NE;
            s_ = d_ = i;
        }
        ss[t] = s_; sd[t] = d_;
    }
    __syncthreads();

    // stage m_in = concat(x[dst], x[src]) into mA[k][e], k = thread
    {
        const int c = t;            // 0..255
        const int cc = c & 127;
        const int side = c >> 7;    // 0 -> dst, 1 -> src
#pragma unroll
        for (int e = 0; e < 32; ++e) {
            int node = side ? ss[e] : sd[e];
            mA[c * 36 + e] = x[node * H + cc];
        }
    }
    __syncthreads();

    const int cg = t & 63;          // 64 col groups of 4
    const int eg = t >> 6;          // 4 edge groups of 8
    const int c0 = cg * 4;
    const int eb = eg * 8;
    float acc[32];

    // ---- layer 1: [32,256]@[256,256], tanh
#pragma unroll
    for (int i = 0; i < 32; ++i) acc[i] = 0.f;
    for (int k = 0; k < 256; ++k) {
        const float4 w  = *(const float4*)(W1 + k * 256 + c0);
        const float4 a0 = *(const float4*)(mA + k * 36 + eb);
        const float4 a1 = *(const float4*)(mA + k * 36 + eb + 4);
        const float wv[4] = {w.x, w.y, w.z, w.w};
        const float av[8] = {a0.x, a0.y, a0.z, a0.w, a1.x, a1.y, a1.z, a1.w};
#pragma unroll
        for (int cc = 0; cc < 4; ++cc)
#pragma unroll
            for (int j = 0; j < 8; ++j) acc[cc * 8 + j] += wv[cc] * av[j];
    }
#pragma unroll
    for (int cc = 0; cc < 4; ++cc) {
        float bv = b1[c0 + cc];
#pragma unroll
        for (int j = 0; j < 8; ++j)
            mB[(c0 + cc) * 36 + eb + j] = tanhf(acc[cc * 8 + j] + bv);
    }
    __syncthreads();

    // ---- layer 2: [32,256]@[256,256], tanh (read mB, write mA; m_in dead)
#pragma unroll
    for (int i = 0; i < 32; ++i) acc[i] = 0.f;
    for (int k = 0; k < 256; ++k) {
        const float4 w  = *(const float4*)(W2 + k * 256 + c0);
        const float4 a0 = *(const float4*)(mB + k * 36 + eb);
        const float4 a1 = *(const float4*)(mB + k * 36 + eb + 4);
        const float wv[4] = {w.x, w.y, w.z, w.w};
        const float av[8] = {a0.x, a0.y, a0.z, a0.w, a1.x, a1.y, a1.z, a1.w};
#pragma unroll
        for (int cc = 0; cc < 4; ++cc)
#pragma unroll
            for (int j = 0; j < 8; ++j) acc[cc * 8 + j] += wv[cc] * av[j];
    }
#pragma unroll
    for (int cc = 0; cc < 4; ++cc) {
        float bv = b2[c0 + cc];
#pragma unroll
        for (int j = 0; j < 8; ++j)
            mA[(c0 + cc) * 36 + eb + j] = tanhf(acc[cc * 8 + j] + bv);
    }
    __syncthreads();

    // ---- layer 3: [32,256]@[256,128], + bias, atomic aggregate by dst
    {
        const int cg3 = t & 31;     // 32 col groups of 4 -> 128 cols
        const int eg3 = t >> 5;     // 8 edge groups of 4
        const int c3 = cg3 * 4;
        const int eb3 = eg3 * 4;
        float acc3[16];
#pragma unroll
        for (int i = 0; i < 16; ++i) acc3[i] = 0.f;
        for (int k = 0; k < 256; ++k) {
            const float4 w = *(const float4*)(W3 + k * 128 + c3);
            const float4 a = *(const float4*)(mA + k * 36 + eb3);
            const float wv[4] = {w.x, w.y, w.z, w.w};
            const float av[4] = {a.x, a.y, a.z, a.w};
#pragma unroll
            for (int cc = 0; cc < 4; ++cc)
#pragma unroll
                for (int j = 0; j < 4; ++j) acc3[cc * 4 + j] += wv[cc] * av[j];
        }
#pragma unroll
        for (int j = 0; j < 4; ++j) {
            const int d = sd[eb3 + j];
#pragma unroll
            for (int cc = 0; cc < 4; ++cc)
                atomicAdd(aggr + d * H + c3 + cc, acc3[cc * 4 + j] + b3[c3 + cc]);
        }
    }
}

// ---------------------------------------------------------------- GRU (16 nodes / block)
// thread t: hidden unit h = t&127, node group ng = t>>7 (8 nodes), owns all 6 gate dots.
__global__ __launch_bounds__(256, 2) void gru_kernel(
        float* __restrict__ x, float* __restrict__ aggr, const float* __restrict__ inv_deg,
        const float* __restrict__ Wi, const float* __restrict__ Wh,
        const float* __restrict__ bi, const float* __restrict__ bh) {
    __shared__ float aL[128 * 16];    // [k][n]
    __shared__ float xL[128 * 16];    // [k][n]
    __shared__ float wiL[16 * 384];
    __shared__ float whL[16 * 384];
    const int t = threadIdx.x;
    const int n0 = blockIdx.x * 16;

    // stage inputs
    {
        const int n = t & 15;
        const int k0 = (t >> 4) * 8;
        const int node = n0 + n;
        const float idg = inv_deg[node];
#pragma unroll
        for (int i = 0; i < 8; ++i) {
            int k = k0 + i;
            aL[k * 16 + n] = aggr[node * H + k] * idg;
            xL[k * 16 + n] = x[node * H + k];
        }
    }

    const int h = t & 127;
    const int nb = (t >> 7) * 8;
    float acc[48];
#pragma unroll
    for (int i = 0; i < 48; ++i) acc[i] = 0.f;

    for (int kc = 0; kc < 8; ++kc) {
        __syncthreads();
        // stage 16 K-rows of Wi and Wh
#pragma unroll
        for (int r = 0; r < 24; ++r) {
            int idx = r * 256 + t;              // 0..6143
            wiL[idx] = Wi[kc * 16 * 384 + idx];
            whL[idx] = Wh[kc * 16 * 384 + idx];
        }
        __syncthreads();
#pragma unroll
        for (int k = 0; k < 16; ++k) {
            const float wir = wiL[k * 384 + h];
            const float wiz = wiL[k * 384 + 128 + h];
            const float win = wiL[k * 384 + 256 + h];
            const float whr = whL[k * 384 + h];
            const float whz = whL[k * 384 + 128 + h];
            const float whn = whL[k * 384 + 256 + h];
            const int kk = kc * 16 + k;
            const float4 a0 = *(const float4*)(aL + kk * 16 + nb);
            const float4 a1 = *(const float4*)(aL + kk * 16 + nb + 4);
            const float4 x0 = *(const float4*)(xL + kk * 16 + nb);
            const float4 x1 = *(const float4*)(xL + kk * 16 + nb + 4);
            const float av[8] = {a0.x, a0.y, a0.z, a0.w, a1.x, a1.y, a1.z, a1.w};
            const float xv[8] = {x0.x, x0.y, x0.z, x0.w, x1.x, x1.y, x1.z, x1.w};
#pragma unroll
            for (int i = 0; i < 8; ++i) {
                acc[i * 6 + 0] += av[i] * wir;
                acc[i * 6 + 1] += av[i] * wiz;
                acc[i * 6 + 2] += av[i] * win;
                acc[i * 6 + 3] += xv[i] * whr;
                acc[i * 6 + 4] += xv[i] * whz;
                acc[i * 6 + 5] += xv[i] * whn;
            }
        }
    }

    const float bir = bi[h], biz = bi[128 + h], bin = bi[256 + h];
    const float bhr = bh[h], bhz = bh[128 + h], bhn = bh[256 + h];
#pragma unroll
    for (int i = 0; i < 8; ++i) {
        const int n = nb + i;
        const int node = n0 + n;
        const float ir = acc[i * 6 + 0] + bir, iz = acc[i * 6 + 1] + biz, inn = acc[i * 6 + 2] + bin;
        const float hr = acc[i * 6 + 3] + bhr, hz = acc[i * 6 + 4] + bhz, hn = acc[i * 6 + 5] + bhn;
        const float r = 1.f / (1.f + expf(-(ir + hr)));
        const float z = 1.f / (1.f + expf(-(iz + hz)));
        const float nn = tanhf(inn + r * hn);
        const float xo = xL[h * 16 + n];
        x[node * H + h] = (1.f - z) * nn + z * xo;
        aggr[node * H + h] = 0.f;     // re-zero for next step's atomics
    }
}

// ---------------------------------------------------------------- decoder (32 masked nodes / block)
__global__ __launch_bounds__(256, 2) void dec_kernel(
        const float* __restrict__ x,
        const float* __restrict__ W1, const float* __restrict__ b1,
        const float* __restrict__ W2, const float* __restrict__ b2,
        const float* __restrict__ W3, const float* __restrict__ b3,
        float* __restrict__ out) {
    __shared__ float bufA[256 * 36];   // xh (rows 0..127), later d2 (rows 0..255)
    __shared__ float d1[256 * 36];
    const int t = threadIdx.x;
    const int id0 = blockIdx.x * 32;

    // stage x for the 32 masked nodes (skip node 8 of each graph)
    {
        const int n = t & 31;
        const int k0 = (t >> 5) * 16;
        const int id = id0 + n;
        const int node = (id >> 3) * NND + (id & 7);
#pragma unroll
        for (int i = 0; i < 16; ++i)
            bufA[(k0 + i) * 36 + n] = x[node * H + k0 + i];
    }
    __syncthreads();

    const int cg = t & 63, ng = t >> 6;
    const int c0 = cg * 4, nb = ng * 8;
    float acc[32];

    // layer 1: K=128 -> 256 cols, tanh
#pragma unroll
    for (int i = 0; i < 32; ++i) acc[i] = 0.f;
    for (int k = 0; k < 128; ++k) {
        const float4 w  = *(const float4*)(W1 + k * 256 + c0);
        const float4 a0 = *(const float4*)(bufA + k * 36 + nb);
        const float4 a1 = *(const float4*)(bufA + k * 36 + nb + 4);
        const float wv[4] = {w.x, w.y, w.z, w.w};
        const float av[8] = {a0.x, a0.y, a0.z, a0.w, a1.x, a1.y, a1.z, a1.w};
#pragma unroll
        for (int cc = 0; cc < 4; ++cc)
#pragma unroll
            for (int j = 0; j < 8; ++j) acc[cc * 8 + j] += wv[cc] * av[j];
    }
    __syncthreads();   // all reads of bufA done before it is overwritten below
#pragma unroll
    for (int cc = 0; cc < 4; ++cc) {
        float bv = b1[c0 + cc];
#pragma unroll
        for (int j = 0; j < 8; ++j)
            d1[(c0 + cc) * 36 + nb + j] = tanhf(acc[cc * 8 + j] + bv);
    }
    __syncthreads();

    // layer 2: K=256 -> 256 cols, tanh (read d1, write bufA)
#pragma unroll
    for (int i = 0; i < 32; ++i) acc[i] = 0.f;
    for (int k = 0; k < 256; ++k) {
        const float4 w  = *(const float4*)(W2 + k * 256 + c0);
        const float4 a0 = *(const float4*)(d1 + k * 36 + nb);
        const float4 a1 = *(const float4*)(d1 + k * 36 + nb + 4);
        const float wv[4] = {w.x, w.y, w.z, w.w};
        const float av[8] = {a0.x, a0.y, a0.z, a0.w, a1.x, a1.y, a1.z, a1.w};
#pragma unroll
        for (int cc = 0; cc < 4; ++cc)
#pragma unroll
            for (int j = 0; j < 8; ++j) acc[cc * 8 + j] += wv[cc] * av[j];
    }
#pragma unroll
    for (int cc = 0; cc < 4; ++cc) {
        float bv = b2[c0 + cc];
#pragma unroll
        for (int j = 0; j < 8; ++j)
            bufA[(c0 + cc) * 36 + nb + j] = tanhf(acc[cc * 8 + j] + bv);
    }
    __syncthreads();

    // layer 3: 256 -> 1, 8 threads per node, shuffle reduce
    {
        const int n3 = t >> 3, p = t & 7;
        float s = 0.f;
#pragma unroll
        for (int i = 0; i < 32; ++i) {
            int k = p * 32 + i;
            s += bufA[k * 36 + n3] * W3[k];
        }
        s += __shfl_down(s, 4, 8);
        s += __shfl_down(s, 2, 8);
        s += __shfl_down(s, 1, 8);
        if (p == 0) out[id0 + n3] = s + b3[0];
    }
}

// ---------------------------------------------------------------- launch
extern "C" void kernel_launch(void* const* d_in, const int* in_sizes, int n_in,
                              void* d_out, int out_size, void* d_ws, size_t ws_size,
                              hipStream_t stream) {
    const float* obs    = (const float*)d_in[0];
    const int*   edges  = (const int*)  d_in[1];
    const float* enc_W  = (const float*)d_in[2];
    const float* enc_b  = (const float*)d_in[3];
    const float* msg_W1 = (const float*)d_in[4];
    const float* msg_b1 = (const float*)d_in[5];
    const float* msg_W2 = (const float*)d_in[6];
    const float* msg_b2 = (const float*)d_in[7];
    const float* msg_W3 = (const float*)d_in[8];
    const float* msg_b3 = (const float*)d_in[9];
    const float* gru_Wi = (const float*)d_in[10];
    const float* gru_Wh = (const float*)d_in[11];
    const float* gru_bi = (const float*)d_in[12];
    const float* gru_bh = (const float*)d_in[13];
    const float* dec_W1 = (const float*)d_in[14];
    const float* dec_b1 = (const float*)d_in[15];
    const float* dec_W2 = (const float*)d_in[16];
    const float* dec_b2 = (const float*)d_in[17];
    const float* dec_W3 = (const float*)d_in[18];
    const float* dec_b3 = (const float*)d_in[19];

    float* x       = (float*)d_ws;                 // BN*128
    float* aggr    = x + (size_t)BN * H;           // BN*128
    float* inv_deg = aggr + (size_t)BN * H;        // BN

    hipMemsetAsync(aggr, 0, (size_t)BN * H * sizeof(float), stream);
    deg_kernel<<<(BGR + 255) / 256, 256, 0, stream>>>(edges, inv_deg);
    enc_kernel<<<BN * H / 256, 256, 0, stream>>>(obs, enc_W, enc_b, x);

    for (int s = 0; s < 4; ++s) {
        msg_kernel<<<ETOT / 32, 256, 0, stream>>>(
            x, edges,
            msg_W1 + (size_t)s * 256 * 256, msg_b1 + (size_t)s * 256,
            msg_W2 + (size_t)s * 256 * 256, msg_b2 + (size_t)s * 256,
            msg_W3 + (size_t)s * 256 * 128, msg_b3 + (size_t)s * 128,
            aggr);
        gru_kernel<<<BN / 16, 256, 0, stream>>>(
            x, aggr, inv_deg,
            gru_Wi + (size_t)s * 128 * 384, gru_Wh + (size_t)s * 128 * 384,
            gru_bi + (size_t)s * 384, gru_bh + (size_t)s * 384);
    }

    dec_kernel<<<BGR * 8 / 32, 256, 0, stream>>>(
        x, dec_W1, dec_b1, dec_W2, dec_b2, dec_W3, dec_b3, (float*)d_out);
}

// Round 2
// 2683.230 us; speedup vs baseline: 2.0723x; 2.0723x over previous
//
#include <hip/hip_runtime.h>
#include <hip/hip_bf16.h>
#include <math.h>

#define BGR   8192        // graphs
#define NND   9           // nodes per graph
#define BN    73728       // BGR*NND
#define NE    131072      // BGR*16 explicit edges
#define ETOT  204800      // NE + BN (self loops)
#define H     128
#define MH    256
#define FIN   15

typedef __bf16 bf16_t;
typedef bf16_t bf16x8 __attribute__((ext_vector_type(8)));
typedef float  f32x4  __attribute__((ext_vector_type(4)));

__device__ __forceinline__ unsigned short f2bf(float f) {
    unsigned int u = __float_as_uint(f);
    u += 0x7fff + ((u >> 16) & 1);           // RNE (inputs are finite)
    return (unsigned short)(u >> 16);
}
__device__ __forceinline__ bf16x8 as_frag(int4 v) {
    union { int4 i; bf16x8 f; } u; u.i = v; return u.f;
}
__device__ __forceinline__ float fast_tanh(float v) {
    float e = __expf(2.0f * v);
    return 1.0f - __fdividef(2.0f, e + 1.0f);
}
// swizzled LDS offset (elements) for element (m, k) in a 64 x 256 bf16 tile
__device__ __forceinline__ int sw_off(int m, int k) {
    return m * 256 + ((((k >> 3) ^ (m & 7)) << 3) | (k & 7));
}

// ---------------------------------------------------------------- deg kernel
__global__ void deg_kernel(const int* __restrict__ edges, float* __restrict__ inv_deg) {
    int g = blockIdx.x * 256 + threadIdx.x;
    if (g >= BGR) return;
    int cnt[NND];
#pragma unroll
    for (int n = 0; n < NND; ++n) cnt[n] = 1;   // self loop
    for (int j = 0; j < 16; ++j) {
        int d = edges[g * 32 + 16 + j];
#pragma unroll
        for (int n = 0; n < NND; ++n) cnt[n] += (d == n) ? 1 : 0;
    }
#pragma unroll
    for (int n = 0; n < NND; ++n) inv_deg[g * NND + n] = 1.0f / (float)cnt[n];
}

// ---------------------------------------------------------------- encoder
__global__ void enc_kernel(const float* __restrict__ obs, const float* __restrict__ W,
                           const float* __restrict__ b, float* __restrict__ x) {
    int tid = blockIdx.x * 256 + threadIdx.x;     // BN*128 threads
    int i = tid >> 7, h = tid & 127;
    float acc = b[h];
#pragma unroll
    for (int k = 0; k < FIN; ++k) acc += obs[i * FIN + k] * W[k * H + h];
    x[i * H + h] = tanhf(acc);
}

// ---------------------------------------------------------------- weight transpose+bf16
// out layout: [ W1T: 4 x 256 x 256 ][ W2T: 4 x 256 x 256 ][ W3T: 4 x 128 x 256 ]  (all [s][n][k])
__global__ void wt_kernel(const float* __restrict__ W1, const float* __restrict__ W2,
                          const float* __restrict__ W3, unsigned short* __restrict__ out) {
    int idx = blockIdx.x * 256 + threadIdx.x;     // 655360 total
    float v;
    if (idx < 262144) {
        int s = idx >> 16, r = idx & 65535, n = r >> 8, k = r & 255;
        v = W1[(s << 16) + (k << 8) + n];
    } else if (idx < 524288) {
        int i2 = idx - 262144;
        int s = i2 >> 16, r = i2 & 65535, n = r >> 8, k = r & 255;
        v = W2[(s << 16) + (k << 8) + n];
    } else {
        int i3 = idx - 524288;
        int s = i3 >> 15, r = i3 & 32767, n = r >> 8, k = r & 255;
        v = W3[(s << 15) + (k << 7) + n];
    }
    out[idx] = f2bf(v);
}

// ---------------------------------------------------------------- fused msg MLP, MFMA bf16
// 64 edges / block, 256 threads (4 waves). Wave w: n-range w*64 for layers 1-2.
__global__ __launch_bounds__(256, 2) void msg_mfma(
        const float* __restrict__ x, const int* __restrict__ edges,
        const unsigned short* __restrict__ W1T, const float* __restrict__ b1,
        const unsigned short* __restrict__ W2T, const float* __restrict__ b2,
        const unsigned short* __restrict__ W3T, const float* __restrict__ b3,
        float* __restrict__ aggr) {
    __shared__ unsigned short bufA[64 * 256];   // 32 KB, swizzled [m][k]
    __shared__ unsigned short bufB[64 * 256];   // 32 KB
    const int t  = threadIdx.x;
    const int e0 = blockIdx.x * 64;
    const int wv = t >> 6;
    const int ln = t & 63;
    const int lrow = ln & 15;     // N-col (B/C) or M-row (A) within tile
    const int lq   = ln >> 4;     // quad

    // ---- stage A0 = bf16(concat(x[dst], x[src])) into bufA
    {
        const int row  = t >> 1;          // 0..127
        const int e    = row & 63;
        const int side = row >> 6;        // 0 -> dst cols 0..127, 1 -> src cols 128..255
        const int eg   = e0 + e;
        int node;
        if (eg < NE) {
            int g = eg >> 4, j = eg & 15;
            node = g * NND + (side ? edges[g * 32 + j] : edges[g * 32 + 16 + j]);
        } else {
            node = eg - NE;
        }
        const int kpart = (t & 1) * 64;
        const float* xs = x + (size_t)node * H + kpart;
        const int kbase = side * 128 + kpart;
#pragma unroll
        for (int i = 0; i < 16; ++i) {
            float4 v = *(const float4*)(xs + i * 4);
            int k0 = kbase + i * 4;
            ushort4 o;
            o.x = f2bf(v.x); o.y = f2bf(v.y); o.z = f2bf(v.z); o.w = f2bf(v.w);
            *(ushort4*)(bufA + sw_off(e, k0)) = o;
        }
    }
    __syncthreads();

    const f32x4 zero = {0.f, 0.f, 0.f, 0.f};
    const int nbase = wv * 64;

    // ---- layer 1: [64,256] @ [256,256]^T-frags, tanh -> bufB
    {
        f32x4 acc[4][4];
#pragma unroll
        for (int i = 0; i < 4; ++i)
#pragma unroll
            for (int j = 0; j < 4; ++j) acc[i][j] = zero;
        for (int kq = 0; kq < 8; ++kq) {
            const int ko = kq * 32 + lq * 8;
            bf16x8 af[4], bfr[4];
#pragma unroll
            for (int tm = 0; tm < 4; ++tm)
                af[tm] = as_frag(*(const int4*)(bufA + sw_off(tm * 16 + lrow, ko)));
#pragma unroll
            for (int tn = 0; tn < 4; ++tn)
                bfr[tn] = as_frag(*(const int4*)(W1T + (size_t)(nbase + tn * 16 + lrow) * 256 + ko));
#pragma unroll
            for (int tm = 0; tm < 4; ++tm)
#pragma unroll
                for (int tn = 0; tn < 4; ++tn)
                    acc[tm][tn] = __builtin_amdgcn_mfma_f32_16x16x32_bf16(af[tm], bfr[tn], acc[tm][tn], 0, 0, 0);
        }
#pragma unroll
        for (int tn = 0; tn < 4; ++tn) {
            const int n = nbase + tn * 16 + lrow;
            const float bias = b1[n];
#pragma unroll
            for (int tm = 0; tm < 4; ++tm)
#pragma unroll
                for (int r = 0; r < 4; ++r) {
                    const int m = tm * 16 + lq * 4 + r;
                    bufB[sw_off(m, n)] = f2bf(fast_tanh(acc[tm][tn][r] + bias));
                }
        }
    }
    __syncthreads();

    // ---- layer 2: bufB @ W2T, tanh -> bufA
    {
        f32x4 acc[4][4];
#pragma unroll
        for (int i = 0; i < 4; ++i)
#pragma unroll
            for (int j = 0; j < 4; ++j) acc[i][j] = zero;
        for (int kq = 0; kq < 8; ++kq) {
            const int ko = kq * 32 + lq * 8;
            bf16x8 af[4], bfr[4];
#pragma unroll
            for (int tm = 0; tm < 4; ++tm)
                af[tm] = as_frag(*(const int4*)(bufB + sw_off(tm * 16 + lrow, ko)));
#pragma unroll
            for (int tn = 0; tn < 4; ++tn)
                bfr[tn] = as_frag(*(const int4*)(W2T + (size_t)(nbase + tn * 16 + lrow) * 256 + ko));
#pragma unroll
            for (int tm = 0; tm < 4; ++tm)
#pragma unroll
                for (int tn = 0; tn < 4; ++tn)
                    acc[tm][tn] = __builtin_amdgcn_mfma_f32_16x16x32_bf16(af[tm], bfr[tn], acc[tm][tn], 0, 0, 0);
        }
#pragma unroll
        for (int tn = 0; tn < 4; ++tn) {
            const int n = nbase + tn * 16 + lrow;
            const float bias = b2[n];
#pragma unroll
            for (int tm = 0; tm < 4; ++tm)
#pragma unroll
                for (int r = 0; r < 4; ++r) {
                    const int m = tm * 16 + lq * 4 + r;
                    bufA[sw_off(m, n)] = f2bf(fast_tanh(acc[tm][tn][r] + bias));
                }
        }
    }
    __syncthreads();

    // ---- layer 3: bufA @ W3T (N=128), + bias, atomic scatter to aggr[dst]
    {
        const int mh = wv >> 1;           // m-half: rows mh*32 .. +31
        const int nh = wv & 1;            // n-half: cols nh*64 .. +63
        f32x4 acc[2][4];
#pragma unroll
        for (int i = 0; i < 2; ++i)
#pragma unroll
            for (int j = 0; j < 4; ++j) acc[i][j] = zero;
        for (int kq = 0; kq < 8; ++kq) {
            const int ko = kq * 32 + lq * 8;
            bf16x8 af[2], bfr[4];
#pragma unroll
            for (int tm = 0; tm < 2; ++tm)
                af[tm] = as_frag(*(const int4*)(bufA + sw_off(mh * 32 + tm * 16 + lrow, ko)));
#pragma unroll
            for (int tn = 0; tn < 4; ++tn)
                bfr[tn] = as_frag(*(const int4*)(W3T + (size_t)(nh * 64 + tn * 16 + lrow) * 256 + ko));
#pragma unroll
            for (int tm = 0; tm < 2; ++tm)
#pragma unroll
                for (int tn = 0; tn < 4; ++tn)
                    acc[tm][tn] = __builtin_amdgcn_mfma_f32_16x16x32_bf16(af[tm], bfr[tn], acc[tm][tn], 0, 0, 0);
        }
#pragma unroll
        for (int tm = 0; tm < 2; ++tm)
#pragma unroll
            for (int r = 0; r < 4; ++r) {
                const int m = mh * 32 + tm * 16 + lq * 4 + r;
                const int eg = e0 + m;
                int d;
                if (eg < NE) {
                    int g = eg >> 4;
                    d = g * NND + edges[g * 32 + 16 + (eg & 15)];
                } else {
                    d = eg - NE;
                }
                float* ap = aggr + (size_t)d * H;
#pragma unroll
                for (int tn = 0; tn < 4; ++tn) {
                    const int n = nh * 64 + tn * 16 + lrow;
                    atomicAdd(ap + n, acc[tm][tn][r] + b3[n]);
                }
            }
    }
}

// ---------------------------------------------------------------- GRU (16 nodes / block)
__global__ __launch_bounds__(256, 2) void gru_kernel(
        float* __restrict__ x, float* __restrict__ aggr, const float* __restrict__ inv_deg,
        const float* __restrict__ Wi, const float* __restrict__ Wh,
        const float* __restrict__ bi, const float* __restrict__ bh) {
    __shared__ float aL[128 * 16];    // [k][n]
    __shared__ float xL[128 * 16];    // [k][n]
    __shared__ float wiL[16 * 384];
    __shared__ float whL[16 * 384];
    const int t = threadIdx.x;
    const int n0 = blockIdx.x * 16;

    {
        const int n = t & 15;
        const int k0 = (t >> 4) * 8;
        const int node = n0 + n;
        const float idg = inv_deg[node];
#pragma unroll
        for (int i = 0; i < 8; ++i) {
            int k = k0 + i;
            aL[k * 16 + n] = aggr[node * H + k] * idg;
            xL[k * 16 + n] = x[node * H + k];
        }
    }

    const int h = t & 127;
    const int nb = (t >> 7) * 8;
    float acc[48];
#pragma unroll
    for (int i = 0; i < 48; ++i) acc[i] = 0.f;

    for (int kc = 0; kc < 8; ++kc) {
        __syncthreads();
#pragma unroll
        for (int r = 0; r < 24; ++r) {
            int idx = r * 256 + t;
            wiL[idx] = Wi[kc * 16 * 384 + idx];
            whL[idx] = Wh[kc * 16 * 384 + idx];
        }
        __syncthreads();
#pragma unroll
        for (int k = 0; k < 16; ++k) {
            const float wir = wiL[k * 384 + h];
            const float wiz = wiL[k * 384 + 128 + h];
            const float win = wiL[k * 384 + 256 + h];
            const float whr = whL[k * 384 + h];
            const float whz = whL[k * 384 + 128 + h];
            const float whn = whL[k * 384 + 256 + h];
            const int kk = kc * 16 + k;
            const float4 a0 = *(const float4*)(aL + kk * 16 + nb);
            const float4 a1 = *(const float4*)(aL + kk * 16 + nb + 4);
            const float4 x0 = *(const float4*)(xL + kk * 16 + nb);
            const float4 x1 = *(const float4*)(xL + kk * 16 + nb + 4);
            const float av[8] = {a0.x, a0.y, a0.z, a0.w, a1.x, a1.y, a1.z, a1.w};
            const float xv[8] = {x0.x, x0.y, x0.z, x0.w, x1.x, x1.y, x1.z, x1.w};
#pragma unroll
            for (int i = 0; i < 8; ++i) {
                acc[i * 6 + 0] += av[i] * wir;
                acc[i * 6 + 1] += av[i] * wiz;
                acc[i * 6 + 2] += av[i] * win;
                acc[i * 6 + 3] += xv[i] * whr;
                acc[i * 6 + 4] += xv[i] * whz;
                acc[i * 6 + 5] += xv[i] * whn;
            }
        }
    }

    const float bir = bi[h], biz = bi[128 + h], bin = bi[256 + h];
    const float bhr = bh[h], bhz = bh[128 + h], bhn = bh[256 + h];
#pragma unroll
    for (int i = 0; i < 8; ++i) {
        const int n = nb + i;
        const int node = n0 + n;
        const float ir = acc[i * 6 + 0] + bir, iz = acc[i * 6 + 1] + biz, inn = acc[i * 6 + 2] + bin;
        const float hr = acc[i * 6 + 3] + bhr, hz = acc[i * 6 + 4] + bhz, hn = acc[i * 6 + 5] + bhn;
        const float r = 1.f / (1.f + expf(-(ir + hr)));
        const float z = 1.f / (1.f + expf(-(iz + hz)));
        const float nn = tanhf(inn + r * hn);
        const float xo = xL[h * 16 + n];
        x[node * H + h] = (1.f - z) * nn + z * xo;
        aggr[node * H + h] = 0.f;     // re-zero for next step's atomics
    }
}

// ---------------------------------------------------------------- decoder (32 masked nodes / block)
__global__ __launch_bounds__(256, 2) void dec_kernel(
        const float* __restrict__ x,
        const float* __restrict__ W1, const float* __restrict__ b1,
        const float* __restrict__ W2, const float* __restrict__ b2,
        const float* __restrict__ W3, const float* __restrict__ b3,
        float* __restrict__ out) {
    __shared__ float bufA[256 * 36];
    __shared__ float d1[256 * 36];
    const int t = threadIdx.x;
    const int id0 = blockIdx.x * 32;

    {
        const int n = t & 31;
        const int k0 = (t >> 5) * 16;
        const int id = id0 + n;
        const int node = (id >> 3) * NND + (id & 7);
#pragma unroll
        for (int i = 0; i < 16; ++i)
            bufA[(k0 + i) * 36 + n] = x[node * H + k0 + i];
    }
    __syncthreads();

    const int cg = t & 63, ng = t >> 6;
    const int c0 = cg * 4, nb = ng * 8;
    float acc[32];

#pragma unroll
    for (int i = 0; i < 32; ++i) acc[i] = 0.f;
    for (int k = 0; k < 128; ++k) {
        const float4 w  = *(const float4*)(W1 + k * 256 + c0);
        const float4 a0 = *(const float4*)(bufA + k * 36 + nb);
        const float4 a1 = *(const float4*)(bufA + k * 36 + nb + 4);
        const float wv[4] = {w.x, w.y, w.z, w.w};
        const float av[8] = {a0.x, a0.y, a0.z, a0.w, a1.x, a1.y, a1.z, a1.w};
#pragma unroll
        for (int cc = 0; cc < 4; ++cc)
#pragma unroll
            for (int j = 0; j < 8; ++j) acc[cc * 8 + j] += wv[cc] * av[j];
    }
    __syncthreads();
#pragma unroll
    for (int cc = 0; cc < 4; ++cc) {
        float bv = b1[c0 + cc];
#pragma unroll
        for (int j = 0; j < 8; ++j)
            d1[(c0 + cc) * 36 + nb + j] = tanhf(acc[cc * 8 + j] + bv);
    }
    __syncthreads();

#pragma unroll
    for (int i = 0; i < 32; ++i) acc[i] = 0.f;
    for (int k = 0; k < 256; ++k) {
        const float4 w  = *(const float4*)(W2 + k * 256 + c0);
        const float4 a0 = *(const float4*)(d1 + k * 36 + nb);
        const float4 a1 = *(const float4*)(d1 + k * 36 + nb + 4);
        const float wv[4] = {w.x, w.y, w.z, w.w};
        const float av[8] = {a0.x, a0.y, a0.z, a0.w, a1.x, a1.y, a1.z, a1.w};
#pragma unroll
        for (int cc = 0; cc < 4; ++cc)
#pragma unroll
            for (int j = 0; j < 8; ++j) acc[cc * 8 + j] += wv[cc] * av[j];
    }
#pragma unroll
    for (int cc = 0; cc < 4; ++cc) {
        float bv = b2[c0 + cc];
#pragma unroll
        for (int j = 0; j < 8; ++j)
            bufA[(c0 + cc) * 36 + nb + j] = tanhf(acc[cc * 8 + j] + bv);
    }
    __syncthreads();

    {
        const int n3 = t >> 3, p = t & 7;
        float s = 0.f;
#pragma unroll
        for (int i = 0; i < 32; ++i) {
            int k = p * 32 + i;
            s += bufA[k * 36 + n3] * W3[k];
        }
        s += __shfl_down(s, 4, 8);
        s += __shfl_down(s, 2, 8);
        s += __shfl_down(s, 1, 8);
        if (p == 0) out[id0 + n3] = s + b3[0];
    }
}

// ---------------------------------------------------------------- launch
extern "C" void kernel_launch(void* const* d_in, const int* in_sizes, int n_in,
                              void* d_out, int out_size, void* d_ws, size_t ws_size,
                              hipStream_t stream) {
    const float* obs    = (const float*)d_in[0];
    const int*   edges  = (const int*)  d_in[1];
    const float* enc_W  = (const float*)d_in[2];
    const float* enc_b  = (const float*)d_in[3];
    const float* msg_W1 = (const float*)d_in[4];
    const float* msg_b1 = (const float*)d_in[5];
    const float* msg_W2 = (const float*)d_in[6];
    const float* msg_b2 = (const float*)d_in[7];
    const float* msg_W3 = (const float*)d_in[8];
    const float* msg_b3 = (const float*)d_in[9];
    const float* gru_Wi = (const float*)d_in[10];
    const float* gru_Wh = (const float*)d_in[11];
    const float* gru_bi = (const float*)d_in[12];
    const float* gru_bh = (const float*)d_in[13];
    const float* dec_W1 = (const float*)d_in[14];
    const float* dec_b1 = (const float*)d_in[15];
    const float* dec_W2 = (const float*)d_in[16];
    const float* dec_b2 = (const float*)d_in[17];
    const float* dec_W3 = (const float*)d_in[18];
    const float* dec_b3 = (const float*)d_in[19];

    float* x       = (float*)d_ws;                 // BN*128
    float* aggr    = x + (size_t)BN * H;           // BN*128
    float* inv_deg = aggr + (size_t)BN * H;        // BN
    unsigned short* wbf = (unsigned short*)(inv_deg + BN);   // 655360 bf16

    hipMemsetAsync(aggr, 0, (size_t)BN * H * sizeof(float), stream);
    deg_kernel<<<(BGR + 255) / 256, 256, 0, stream>>>(edges, inv_deg);
    wt_kernel<<<655360 / 256, 256, 0, stream>>>(msg_W1, msg_W2, msg_W3, wbf);
    enc_kernel<<<BN * H / 256, 256, 0, stream>>>(obs, enc_W, enc_b, x);

    for (int s = 0; s < 4; ++s) {
        const unsigned short* W1T = wbf + (size_t)s * 65536;
        const unsigned short* W2T = wbf + 262144 + (size_t)s * 65536;
        const unsigned short* W3T = wbf + 524288 + (size_t)s * 32768;
        msg_mfma<<<ETOT / 64, 256, 0, stream>>>(
            x, edges,
            W1T, msg_b1 + (size_t)s * 256,
            W2T, msg_b2 + (size_t)s * 256,
            W3T, msg_b3 + (size_t)s * 128,
            aggr);
        gru_kernel<<<BN / 16, 256, 0, stream>>>(
            x, aggr, inv_deg,
            gru_Wi + (size_t)s * 128 * 384, gru_Wh + (size_t)s * 128 * 384,
            gru_bi + (size_t)s * 384, gru_bh + (size_t)s * 384);
    }

    dec_kernel<<<BGR * 8 / 32, 256, 0, stream>>>(
        x, dec_W1, dec_b1, dec_W2, dec_b2, dec_W3, dec_b3, (float*)d_out);
}

// Round 3
// 1645.746 us; speedup vs baseline: 3.3787x; 1.6304x over previous
//
#include <hip/hip_runtime.h>
#include <hip/hip_bf16.h>
#include <math.h>

#define BGR   8192        // graphs
#define NND   9           // nodes per graph
#define BN    73728       // BGR*NND
#define NE    131072      // BGR*16 explicit edges
#define ETOT  204800      // NE + BN (self loops)
#define H     128
#define MH    256
#define FIN   15

typedef __bf16 bf16_t;
typedef bf16_t bf16x8 __attribute__((ext_vector_type(8)));
typedef float  f32x4  __attribute__((ext_vector_type(4)));

__device__ __forceinline__ unsigned short f2bf(float f) {
    unsigned int u = __float_as_uint(f);
    u += 0x7fff + ((u >> 16) & 1);           // RNE (inputs are finite)
    return (unsigned short)(u >> 16);
}
__device__ __forceinline__ bf16x8 as_frag(int4 v) {
    union { int4 i; bf16x8 f; } u; u.i = v; return u.f;
}
__device__ __forceinline__ float fast_tanh(float v) {
    float e = __expf(2.0f * v);
    return 1.0f - __fdividef(2.0f, e + 1.0f);
}
// swizzled LDS offset (elements) for element (m, k) in a 64 x 256 bf16 tile
__device__ __forceinline__ int sw_off(int m, int k) {
    return m * 256 + ((((k >> 3) ^ (m & 7)) << 3) | (k & 7));
}

// ---------------------------------------------------------------- deg kernel
__global__ void deg_kernel(const int* __restrict__ edges, float* __restrict__ inv_deg) {
    int g = blockIdx.x * 256 + threadIdx.x;
    if (g >= BGR) return;
    int cnt[NND];
#pragma unroll
    for (int n = 0; n < NND; ++n) cnt[n] = 1;   // self loop
    for (int j = 0; j < 16; ++j) {
        int d = edges[g * 32 + 16 + j];
#pragma unroll
        for (int n = 0; n < NND; ++n) cnt[n] += (d == n) ? 1 : 0;
    }
#pragma unroll
    for (int n = 0; n < NND; ++n) inv_deg[g * NND + n] = 1.0f / (float)cnt[n];
}

// ---------------------------------------------------------------- encoder
__global__ void enc_kernel(const float* __restrict__ obs, const float* __restrict__ W,
                           const float* __restrict__ b, float* __restrict__ x) {
    int tid = blockIdx.x * 256 + threadIdx.x;     // BN*128 threads
    int i = tid >> 7, h = tid & 127;
    float acc = b[h];
#pragma unroll
    for (int k = 0; k < FIN; ++k) acc += obs[i * FIN + k] * W[k * H + h];
    x[i * H + h] = tanhf(acc);
}

// ---------------------------------------------------------------- weight transpose+bf16
// out: [ W1T: 4x256x256 ][ W2T: 4x256x256 ][ W3T: 4x128x256 ][ WG: 4x512x256 ]
// WG packed col p = w*128 + gate*32 + hh*16 + c  ->  (gate, h = w*32 + hh*16 + c)
//   gate0 (r):  k<128 ? Wi[k][h]     : Wh[k-128][h]        (ir+hr fused)
//   gate1 (z):  k<128 ? Wi[k][128+h] : Wh[k-128][128+h]    (iz+hz fused)
//   gate2 (n):  k<128 ? Wi[k][256+h] : 0                   (inn)
//   gate3 (hn): k<128 ? 0            : Wh[k-128][256+h]    (hn)
__global__ void wt_kernel(const float* __restrict__ W1, const float* __restrict__ W2,
                          const float* __restrict__ W3, const float* __restrict__ Wi,
                          const float* __restrict__ Wh, unsigned short* __restrict__ out) {
    int idx = blockIdx.x * 256 + threadIdx.x;     // 1179648 total
    float v;
    if (idx < 262144) {
        int s = idx >> 16, r = idx & 65535, n = r >> 8, k = r & 255;
        v = W1[(s << 16) + (k << 8) + n];
    } else if (idx < 524288) {
        int i2 = idx - 262144;
        int s = i2 >> 16, r = i2 & 65535, n = r >> 8, k = r & 255;
        v = W2[(s << 16) + (k << 8) + n];
    } else if (idx < 655360) {
        int i3 = idx - 524288;
        int s = i3 >> 15, r = i3 & 32767, n = r >> 8, k = r & 255;
        v = W3[(s << 15) + (k << 7) + n];
    } else {
        int i4 = idx - 655360;                    // 0..524287
        int s = i4 >> 17, rr = i4 & 131071;
        int p = rr >> 8, k = rr & 255;
        int w = p >> 7, rem = p & 127;
        int gate = rem >> 5, hh = (rem >> 4) & 1, c = rem & 15;
        int h = w * 32 + hh * 16 + c;
        const int sb = s * 49152;                 // 128*384
        if (gate == 0)      v = (k < 128) ? Wi[sb + k * 384 + h]       : Wh[sb + (k - 128) * 384 + h];
        else if (gate == 1) v = (k < 128) ? Wi[sb + k * 384 + 128 + h] : Wh[sb + (k - 128) * 384 + 128 + h];
        else if (gate == 2) v = (k < 128) ? Wi[sb + k * 384 + 256 + h] : 0.f;
        else                v = (k < 128) ? 0.f                        : Wh[sb + (k - 128) * 384 + 256 + h];
    }
    out[idx] = f2bf(v);
}

// ---------------------------------------------------------------- fused msg MLP, MFMA bf16
__global__ __launch_bounds__(256, 2) void msg_mfma(
        const float* __restrict__ x, const int* __restrict__ edges,
        const unsigned short* __restrict__ W1T, const float* __restrict__ b1,
        const unsigned short* __restrict__ W2T, const float* __restrict__ b2,
        const unsigned short* __restrict__ W3T, const float* __restrict__ b3,
        float* __restrict__ aggr) {
    __shared__ unsigned short bufA[64 * 256];   // 32 KB, swizzled [m][k]
    __shared__ unsigned short bufB[64 * 256];   // 32 KB
    const int t  = threadIdx.x;
    const int e0 = blockIdx.x * 64;
    const int wv = t >> 6;
    const int ln = t & 63;
    const int lrow = ln & 15;
    const int lq   = ln >> 4;

    // ---- stage A0 = bf16(concat(x[dst], x[src])) into bufA
    {
        const int row  = t >> 1;          // 0..127
        const int e    = row & 63;
        const int side = row >> 6;        // 0 -> dst cols 0..127, 1 -> src cols 128..255
        const int eg   = e0 + e;
        int node;
        if (eg < NE) {
            int g = eg >> 4, j = eg & 15;
            node = g * NND + (side ? edges[g * 32 + j] : edges[g * 32 + 16 + j]);
        } else {
            node = eg - NE;
        }
        const int kpart = (t & 1) * 64;
        const float* xs = x + (size_t)node * H + kpart;
        const int kbase = side * 128 + kpart;
#pragma unroll
        for (int i = 0; i < 16; ++i) {
            float4 v = *(const float4*)(xs + i * 4);
            int k0 = kbase + i * 4;
            ushort4 o;
            o.x = f2bf(v.x); o.y = f2bf(v.y); o.z = f2bf(v.z); o.w = f2bf(v.w);
            *(ushort4*)(bufA + sw_off(e, k0)) = o;
        }
    }
    __syncthreads();

    const f32x4 zero = {0.f, 0.f, 0.f, 0.f};
    const int nbase = wv * 64;

    // ---- layer 1
    {
        f32x4 acc[4][4];
#pragma unroll
        for (int i = 0; i < 4; ++i)
#pragma unroll
            for (int j = 0; j < 4; ++j) acc[i][j] = zero;
        for (int kq = 0; kq < 8; ++kq) {
            const int ko = kq * 32 + lq * 8;
            bf16x8 af[4], bfr[4];
#pragma unroll
            for (int tm = 0; tm < 4; ++tm)
                af[tm] = as_frag(*(const int4*)(bufA + sw_off(tm * 16 + lrow, ko)));
#pragma unroll
            for (int tn = 0; tn < 4; ++tn)
                bfr[tn] = as_frag(*(const int4*)(W1T + (size_t)(nbase + tn * 16 + lrow) * 256 + ko));
#pragma unroll
            for (int tm = 0; tm < 4; ++tm)
#pragma unroll
                for (int tn = 0; tn < 4; ++tn)
                    acc[tm][tn] = __builtin_amdgcn_mfma_f32_16x16x32_bf16(af[tm], bfr[tn], acc[tm][tn], 0, 0, 0);
        }
#pragma unroll
        for (int tn = 0; tn < 4; ++tn) {
            const int n = nbase + tn * 16 + lrow;
            const float bias = b1[n];
#pragma unroll
            for (int tm = 0; tm < 4; ++tm)
#pragma unroll
                for (int r = 0; r < 4; ++r) {
                    const int m = tm * 16 + lq * 4 + r;
                    bufB[sw_off(m, n)] = f2bf(fast_tanh(acc[tm][tn][r] + bias));
                }
        }
    }
    __syncthreads();

    // ---- layer 2
    {
        f32x4 acc[4][4];
#pragma unroll
        for (int i = 0; i < 4; ++i)
#pragma unroll
            for (int j = 0; j < 4; ++j) acc[i][j] = zero;
        for (int kq = 0; kq < 8; ++kq) {
            const int ko = kq * 32 + lq * 8;
            bf16x8 af[4], bfr[4];
#pragma unroll
            for (int tm = 0; tm < 4; ++tm)
                af[tm] = as_frag(*(const int4*)(bufB + sw_off(tm * 16 + lrow, ko)));
#pragma unroll
            for (int tn = 0; tn < 4; ++tn)
                bfr[tn] = as_frag(*(const int4*)(W2T + (size_t)(nbase + tn * 16 + lrow) * 256 + ko));
#pragma unroll
            for (int tm = 0; tm < 4; ++tm)
#pragma unroll
                for (int tn = 0; tn < 4; ++tn)
                    acc[tm][tn] = __builtin_amdgcn_mfma_f32_16x16x32_bf16(af[tm], bfr[tn], acc[tm][tn], 0, 0, 0);
        }
#pragma unroll
        for (int tn = 0; tn < 4; ++tn) {
            const int n = nbase + tn * 16 + lrow;
            const float bias = b2[n];
#pragma unroll
            for (int tm = 0; tm < 4; ++tm)
#pragma unroll
                for (int r = 0; r < 4; ++r) {
                    const int m = tm * 16 + lq * 4 + r;
                    bufA[sw_off(m, n)] = f2bf(fast_tanh(acc[tm][tn][r] + bias));
                }
        }
    }
    __syncthreads();

    // ---- layer 3: N=128, + bias, atomic scatter to aggr[dst]
    {
        const int mh = wv >> 1;
        const int nh = wv & 1;
        f32x4 acc[2][4];
#pragma unroll
        for (int i = 0; i < 2; ++i)
#pragma unroll
            for (int j = 0; j < 4; ++j) acc[i][j] = zero;
        for (int kq = 0; kq < 8; ++kq) {
            const int ko = kq * 32 + lq * 8;
            bf16x8 af[2], bfr[4];
#pragma unroll
            for (int tm = 0; tm < 2; ++tm)
                af[tm] = as_frag(*(const int4*)(bufA + sw_off(mh * 32 + tm * 16 + lrow, ko)));
#pragma unroll
            for (int tn = 0; tn < 4; ++tn)
                bfr[tn] = as_frag(*(const int4*)(W3T + (size_t)(nh * 64 + tn * 16 + lrow) * 256 + ko));
#pragma unroll
            for (int tm = 0; tm < 2; ++tm)
#pragma unroll
                for (int tn = 0; tn < 4; ++tn)
                    acc[tm][tn] = __builtin_amdgcn_mfma_f32_16x16x32_bf16(af[tm], bfr[tn], acc[tm][tn], 0, 0, 0);
        }
#pragma unroll
        for (int tm = 0; tm < 2; ++tm)
#pragma unroll
            for (int r = 0; r < 4; ++r) {
                const int m = mh * 32 + tm * 16 + lq * 4 + r;
                const int eg = e0 + m;
                int d;
                if (eg < NE) {
                    int g = eg >> 4;
                    d = g * NND + edges[g * 32 + 16 + (eg & 15)];
                } else {
                    d = eg - NE;
                }
                float* ap = aggr + (size_t)d * H;
#pragma unroll
                for (int tn = 0; tn < 4; ++tn) {
                    const int n = nh * 64 + tn * 16 + lrow;
                    atomicAdd(ap + n, acc[tm][tn][r] + b3[n]);
                }
            }
    }
}

// ---------------------------------------------------------------- GRU via MFMA (64 nodes / block)
// A = bf16([aggr*inv_deg | x])  [64][256];  B = WG packed [512][256] bf16.
// Wave w computes packed cols [w*128, w*128+128); all 4 gate pre-activations of a
// given (node, h) land in the SAME lane across register-indexed n-tiles.
__global__ __launch_bounds__(256, 2) void gru_mfma(
        float* __restrict__ x, float* __restrict__ aggr, const float* __restrict__ inv_deg,
        const unsigned short* __restrict__ WG,
        const float* __restrict__ bi, const float* __restrict__ bh) {
    __shared__ unsigned short bufA[64 * 256];   // 32 KB
    const int t = threadIdx.x;
    const int n0 = blockIdx.x * 64;
    const int wv = t >> 6, ln = t & 63, lrow = ln & 15, lq = ln >> 4;

    // stage A: row m = t>>2, k-quarter q = t&3
    {
        const int m = t >> 2;
        const int q = t & 3;
        const int node = n0 + m;
        const int k0 = q * 64;
        const float scale = (q < 2) ? inv_deg[node] : 1.f;
        const float* src = (q < 2) ? (aggr + (size_t)node * H + k0)
                                   : (x    + (size_t)node * H + (k0 - 128));
#pragma unroll
        for (int i = 0; i < 16; ++i) {
            float4 v = *(const float4*)(src + i * 4);
            ushort4 o;
            o.x = f2bf(v.x * scale); o.y = f2bf(v.y * scale);
            o.z = f2bf(v.z * scale); o.w = f2bf(v.w * scale);
            *(ushort4*)(bufA + sw_off(m, k0 + i * 4)) = o;
        }
    }
    __syncthreads();

    const f32x4 zero = {0.f, 0.f, 0.f, 0.f};
    f32x4 acc[4][8];
#pragma unroll
    for (int i = 0; i < 4; ++i)
#pragma unroll
        for (int j = 0; j < 8; ++j) acc[i][j] = zero;

    for (int kq = 0; kq < 8; ++kq) {
        const int ko = kq * 32 + lq * 8;
        bf16x8 af[4], bfr[8];
#pragma unroll
        for (int tm = 0; tm < 4; ++tm)
            af[tm] = as_frag(*(const int4*)(bufA + sw_off(tm * 16 + lrow, ko)));
#pragma unroll
        for (int jt = 0; jt < 8; ++jt)
            bfr[jt] = as_frag(*(const int4*)(WG + (size_t)(wv * 128 + jt * 16 + lrow) * 256 + ko));
#pragma unroll
        for (int tm = 0; tm < 4; ++tm)
#pragma unroll
            for (int jt = 0; jt < 8; ++jt)
                acc[tm][jt] = __builtin_amdgcn_mfma_f32_16x16x32_bf16(af[tm], bfr[jt], acc[tm][jt], 0, 0, 0);
    }

    // epilogue: thread-local gate mixing; acc[tm][gate*2+hh][r] for h = wv*32+hh*16+lrow
#pragma unroll
    for (int hh = 0; hh < 2; ++hh) {
        const int h = wv * 32 + hh * 16 + lrow;
        const float b_r = bi[h] + bh[h];
        const float b_z = bi[128 + h] + bh[128 + h];
        const float b_n = bi[256 + h];
        const float b_h = bh[256 + h];
#pragma unroll
        for (int tm = 0; tm < 4; ++tm) {
#pragma unroll
            for (int r = 0; r < 4; ++r) {
                const int node = n0 + tm * 16 + lq * 4 + r;
                const float irhr = acc[tm][0 + hh][r] + b_r;
                const float izhz = acc[tm][2 + hh][r] + b_z;
                const float inn  = acc[tm][4 + hh][r] + b_n;
                const float hn   = acc[tm][6 + hh][r] + b_h;
                const float rg = 1.f / (1.f + expf(-irhr));
                const float zg = 1.f / (1.f + expf(-izhz));
                const float ng = tanhf(inn + rg * hn);
                const float xo = x[(size_t)node * H + h];
                x[(size_t)node * H + h] = (1.f - zg) * ng + zg * xo;
                aggr[(size_t)node * H + h] = 0.f;   // re-zero for next step
            }
        }
    }
}

// ---------------------------------------------------------------- decoder (32 masked nodes / block)
__global__ __launch_bounds__(256, 2) void dec_kernel(
        const float* __restrict__ x,
        const float* __restrict__ W1, const float* __restrict__ b1,
        const float* __restrict__ W2, const float* __restrict__ b2,
        const float* __restrict__ W3, const float* __restrict__ b3,
        float* __restrict__ out) {
    __shared__ float bufA[256 * 36];
    __shared__ float d1[256 * 36];
    const int t = threadIdx.x;
    const int id0 = blockIdx.x * 32;

    {
        const int n = t & 31;
        const int k0 = (t >> 5) * 16;
        const int id = id0 + n;
        const int node = (id >> 3) * NND + (id & 7);
#pragma unroll
        for (int i = 0; i < 16; ++i)
            bufA[(k0 + i) * 36 + n] = x[node * H + k0 + i];
    }
    __syncthreads();

    const int cg = t & 63, ng = t >> 6;
    const int c0 = cg * 4, nb = ng * 8;
    float acc[32];

#pragma unroll
    for (int i = 0; i < 32; ++i) acc[i] = 0.f;
    for (int k = 0; k < 128; ++k) {
        const float4 w  = *(const float4*)(W1 + k * 256 + c0);
        const float4 a0 = *(const float4*)(bufA + k * 36 + nb);
        const float4 a1 = *(const float4*)(bufA + k * 36 + nb + 4);
        const float wv[4] = {w.x, w.y, w.z, w.w};
        const float av[8] = {a0.x, a0.y, a0.z, a0.w, a1.x, a1.y, a1.z, a1.w};
#pragma unroll
        for (int cc = 0; cc < 4; ++cc)
#pragma unroll
            for (int j = 0; j < 8; ++j) acc[cc * 8 + j] += wv[cc] * av[j];
    }
    __syncthreads();
#pragma unroll
    for (int cc = 0; cc < 4; ++cc) {
        float bv = b1[c0 + cc];
#pragma unroll
        for (int j = 0; j < 8; ++j)
            d1[(c0 + cc) * 36 + nb + j] = tanhf(acc[cc * 8 + j] + bv);
    }
    __syncthreads();

#pragma unroll
    for (int i = 0; i < 32; ++i) acc[i] = 0.f;
    for (int k = 0; k < 256; ++k) {
        const float4 w  = *(const float4*)(W2 + k * 256 + c0);
        const float4 a0 = *(const float4*)(d1 + k * 36 + nb);
        const float4 a1 = *(const float4*)(d1 + k * 36 + nb + 4);
        const float wv[4] = {w.x, w.y, w.z, w.w};
        const float av[8] = {a0.x, a0.y, a0.z, a0.w, a1.x, a1.y, a1.z, a1.w};
#pragma unroll
        for (int cc = 0; cc < 4; ++cc)
#pragma unroll
            for (int j = 0; j < 8; ++j) acc[cc * 8 + j] += wv[cc] * av[j];
    }
#pragma unroll
    for (int cc = 0; cc < 4; ++cc) {
        float bv = b2[c0 + cc];
#pragma unroll
        for (int j = 0; j < 8; ++j)
            bufA[(c0 + cc) * 36 + nb + j] = tanhf(acc[cc * 8 + j] + bv);
    }
    __syncthreads();

    {
        const int n3 = t >> 3, p = t & 7;
        float s = 0.f;
#pragma unroll
        for (int i = 0; i < 32; ++i) {
            int k = p * 32 + i;
            s += bufA[k * 36 + n3] * W3[k];
        }
        s += __shfl_down(s, 4, 8);
        s += __shfl_down(s, 2, 8);
        s += __shfl_down(s, 1, 8);
        if (p == 0) out[id0 + n3] = s + b3[0];
    }
}

// ---------------------------------------------------------------- launch
extern "C" void kernel_launch(void* const* d_in, const int* in_sizes, int n_in,
                              void* d_out, int out_size, void* d_ws, size_t ws_size,
                              hipStream_t stream) {
    const float* obs    = (const float*)d_in[0];
    const int*   edges  = (const int*)  d_in[1];
    const float* enc_W  = (const float*)d_in[2];
    const float* enc_b  = (const float*)d_in[3];
    const float* msg_W1 = (const float*)d_in[4];
    const float* msg_b1 = (const float*)d_in[5];
    const float* msg_W2 = (const float*)d_in[6];
    const float* msg_b2 = (const float*)d_in[7];
    const float* msg_W3 = (const float*)d_in[8];
    const float* msg_b3 = (const float*)d_in[9];
    const float* gru_Wi = (const float*)d_in[10];
    const float* gru_Wh = (const float*)d_in[11];
    const float* gru_bi = (const float*)d_in[12];
    const float* gru_bh = (const float*)d_in[13];
    const float* dec_W1 = (const float*)d_in[14];
    const float* dec_b1 = (const float*)d_in[15];
    const float* dec_W2 = (const float*)d_in[16];
    const float* dec_b2 = (const float*)d_in[17];
    const float* dec_W3 = (const float*)d_in[18];
    const float* dec_b3 = (const float*)d_in[19];

    float* x       = (float*)d_ws;                 // BN*128
    float* aggr    = x + (size_t)BN * H;           // BN*128
    float* inv_deg = aggr + (size_t)BN * H;        // BN
    unsigned short* wbf = (unsigned short*)(inv_deg + BN);   // 655360 msg bf16 + 524288 gru bf16

    hipMemsetAsync(aggr, 0, (size_t)BN * H * sizeof(float), stream);
    deg_kernel<<<(BGR + 255) / 256, 256, 0, stream>>>(edges, inv_deg);
    wt_kernel<<<1179648 / 256, 256, 0, stream>>>(msg_W1, msg_W2, msg_W3, gru_Wi, gru_Wh, wbf);
    enc_kernel<<<BN * H / 256, 256, 0, stream>>>(obs, enc_W, enc_b, x);

    for (int s = 0; s < 4; ++s) {
        const unsigned short* W1T = wbf + (size_t)s * 65536;
        const unsigned short* W2T = wbf + 262144 + (size_t)s * 65536;
        const unsigned short* W3T = wbf + 524288 + (size_t)s * 32768;
        const unsigned short* WGs = wbf + 655360 + (size_t)s * 131072;
        msg_mfma<<<ETOT / 64, 256, 0, stream>>>(
            x, edges,
            W1T, msg_b1 + (size_t)s * 256,
            W2T, msg_b2 + (size_t)s * 256,
            W3T, msg_b3 + (size_t)s * 128,
            aggr);
        gru_mfma<<<BN / 64, 256, 0, stream>>>(
            x, aggr, inv_deg, WGs,
            gru_bi + (size_t)s * 384, gru_bh + (size_t)s * 384);
    }

    dec_kernel<<<BGR * 8 / 32, 256, 0, stream>>>(
        x, dec_W1, dec_b1, dec_W2, dec_b2, dec_W3, dec_b3, (float*)d_out);
}